// Round 1
// baseline (724.065 us; speedup 1.0000x reference)
//
#include <hip/hip_runtime.h>
#include <math.h>

#define NN 40000
#define INDIM 256
#define HID 128
#define HEADS 4
#define NGAT 3
#define LN_EPS 1e-5f
#define SLOPE 0.2f

__device__ inline float wsum(float v) {
#pragma unroll
  for (int m = 1; m < 64; m <<= 1) v += __shfl_xor(v, m, 64);
  return v;
}
__device__ inline float wmax(float v) {
#pragma unroll
  for (int m = 1; m < 64; m <<= 1) v = fmaxf(v, __shfl_xor(v, m, 64));
  return v;
}
__device__ inline float leaky(float v) { return v > 0.f ? v : SLOPE * v; }

// ---------------- CSR construction ----------------
__global__ void k_deg(const int* __restrict__ ei, int E, int N, int* __restrict__ deg) {
  int e = blockIdx.x * blockDim.x + threadIdx.x;
  if (e >= E + N) return;
  int dst = (e < E) ? ei[E + e] : (e - E);
  atomicAdd(&deg[dst], 1);
}

__global__ void k_scan1(const int* __restrict__ deg, int N, int* __restrict__ bsums) {
  __shared__ int s[256];
  int gid = blockIdx.x * 256 + threadIdx.x;
  s[threadIdx.x] = (gid < N) ? deg[gid] : 0;
  __syncthreads();
  for (int off = 128; off > 0; off >>= 1) {
    if (threadIdx.x < off) s[threadIdx.x] += s[threadIdx.x + off];
    __syncthreads();
  }
  if (threadIdx.x == 0) bsums[blockIdx.x] = s[0];
}

__global__ void k_scan2(int* __restrict__ bsums, int nblk, int* __restrict__ rowptr, int N) {
  if (threadIdx.x == 0 && blockIdx.x == 0) {
    int run = 0;
    for (int i = 0; i < nblk; ++i) { int t = bsums[i]; bsums[i] = run; run += t; }
    rowptr[N] = run;
  }
}

__global__ void k_scan3(const int* __restrict__ deg, int N, const int* __restrict__ bsums,
                        int* __restrict__ rowptr, int* __restrict__ cursor) {
  __shared__ int s[256];
  int gid = blockIdx.x * 256 + threadIdx.x;
  int v = (gid < N) ? deg[gid] : 0;
  s[threadIdx.x] = v;
  __syncthreads();
  for (int off = 1; off < 256; off <<= 1) {
    int t = (threadIdx.x >= off) ? s[threadIdx.x - off] : 0;
    __syncthreads();
    s[threadIdx.x] += t;
    __syncthreads();
  }
  if (gid < N) {
    int ex = bsums[blockIdx.x] + s[threadIdx.x] - v;
    rowptr[gid] = ex;
    cursor[gid] = ex;
  }
}

__global__ void k_fill(const int* __restrict__ ei, int E, int N,
                       int* __restrict__ cursor, int* __restrict__ csr) {
  int e = blockIdx.x * blockDim.x + threadIdx.x;
  if (e >= E + N) return;
  int src, dst;
  if (e < E) { src = ei[e]; dst = ei[E + e]; } else { src = dst = e - E; }
  int pos = atomicAdd(&cursor[dst], 1);
  csr[pos] = src;
}

__global__ void k_dinv(const int* __restrict__ deg, int N, float* __restrict__ dinv) {
  int n = blockIdx.x * blockDim.x + threadIdx.x;
  if (n < N) dinv[n] = rsqrtf((float)deg[n]);
}

// ---------------- fp32 tiled GEMM: C[M,Nc] = A[M,K] @ B[K,Nc] (+bias) ----------------
template <int K, bool BIAS>
__global__ __launch_bounds__(256) void k_gemm(const float* __restrict__ A,
                                              const float* __restrict__ B,
                                              const float* __restrict__ bias,
                                              float* __restrict__ C, int M, int Nc) {
  __shared__ float As[16][68];  // [k][m]
  __shared__ float Bs[16][68];  // [k][n]
  const int tid = threadIdx.x;
  const int m0 = blockIdx.x * 64;
  const int n0 = blockIdx.y * 64;
  const int rowBase = (tid >> 4) * 4;
  const int colBase = (tid & 15) * 4;
  const int la_row = tid >> 2;
  const int la_k = (tid & 3) * 4;
  const int lb_k = tid >> 4;
  const int lb_c = (tid & 15) * 4;
  float acc[4][4] = {};
  const float* Aptr = A + (size_t)(m0 + la_row) * K + la_k;
  const float* Bptr = B + (size_t)lb_k * Nc + n0 + lb_c;
  for (int k0 = 0; k0 < K; k0 += 16) {
    float4 av = *(const float4*)(Aptr + k0);
    float4 bv = *(const float4*)(Bptr + (size_t)k0 * Nc);
    __syncthreads();
    As[la_k + 0][la_row] = av.x;
    As[la_k + 1][la_row] = av.y;
    As[la_k + 2][la_row] = av.z;
    As[la_k + 3][la_row] = av.w;
    *(float4*)&Bs[lb_k][lb_c] = bv;
    __syncthreads();
#pragma unroll
    for (int k = 0; k < 16; ++k) {
      const float4 a = *(const float4*)&As[k][rowBase];
      const float4 b = *(const float4*)&Bs[k][colBase];
      float ar[4] = {a.x, a.y, a.z, a.w};
      float br[4] = {b.x, b.y, b.z, b.w};
#pragma unroll
      for (int i = 0; i < 4; ++i)
#pragma unroll
        for (int j = 0; j < 4; ++j) acc[i][j] = fmaf(ar[i], br[j], acc[i][j]);
    }
  }
#pragma unroll
  for (int i = 0; i < 4; ++i) {
    float4 o;
    o.x = acc[i][0]; o.y = acc[i][1]; o.z = acc[i][2]; o.w = acc[i][3];
    if (BIAS) {
      o.x += bias[n0 + colBase + 0];
      o.y += bias[n0 + colBase + 1];
      o.z += bias[n0 + colBase + 2];
      o.w += bias[n0 + colBase + 3];
    }
    *(float4*)(C + (size_t)(m0 + rowBase + i) * Nc + n0 + colBase) = o;
  }
}

// ---------------- attention logits a_s/a_d: [N, HEADS] ----------------
__global__ __launch_bounds__(256) void k_att(const float* __restrict__ xh,
                                             const float* __restrict__ atts,
                                             const float* __restrict__ attd,
                                             float* __restrict__ a_s,
                                             float* __restrict__ a_d, int N) {
  int lane = threadIdx.x & 63;
  int n = blockIdx.x * 4 + (threadIdx.x >> 6);
  if (n >= N) return;
  const float* row = xh + (size_t)n * (HEADS * HID);
  int base = lane * 8;
  float4 r0 = *(const float4*)(row + base);
  float4 r1 = *(const float4*)(row + base + 4);
  float4 s0 = *(const float4*)(atts + base);
  float4 s1 = *(const float4*)(atts + base + 4);
  float4 d0 = *(const float4*)(attd + base);
  float4 d1 = *(const float4*)(attd + base + 4);
  float ss = r0.x * s0.x + r0.y * s0.y + r0.z * s0.z + r0.w * s0.w +
             r1.x * s1.x + r1.y * s1.y + r1.z * s1.z + r1.w * s1.w;
  float sd = r0.x * d0.x + r0.y * d0.y + r0.z * d0.z + r0.w * d0.w +
             r1.x * d1.x + r1.y * d1.y + r1.z * d1.z + r1.w * d1.w;
#pragma unroll
  for (int m = 1; m < 16; m <<= 1) {
    ss += __shfl_xor(ss, m, 64);
    sd += __shfl_xor(sd, m, 64);
  }
  if ((lane & 15) == 0) {
    int h = lane >> 4;
    a_s[n * HEADS + h] = ss;
    a_d[n * HEADS + h] = sd;
  }
}

// ---------------- GAT aggregation + head-mean + bias + LN + ReLU + residual ----------------
__global__ __launch_bounds__(256) void k_gat_agg(
    const int* __restrict__ rowptr, const int* __restrict__ csr,
    const float* __restrict__ xh, const float* __restrict__ a_s,
    const float* __restrict__ a_d, float* __restrict__ h,
    const float* __restrict__ bias, const float* __restrict__ gamma,
    const float* __restrict__ beta, int N) {
  int lane = threadIdx.x & 63;
  int n = blockIdx.x * 4 + (threadIdx.x >> 6);
  if (n >= N) return;
  int beg = rowptr[n], end = rowptr[n + 1];
  const float4 adv = *(const float4*)(a_d + n * HEADS);
  float ad[4] = {adv.x, adv.y, adv.z, adv.w};
  // pass 1: per-head max over incoming edges (edges parallel over lanes)
  float m[4] = {-1e30f, -1e30f, -1e30f, -1e30f};
  for (int e = beg + lane; e < end; e += 64) {
    int s = csr[e];
    const float4 asv = *(const float4*)(a_s + s * HEADS);
    m[0] = fmaxf(m[0], leaky(asv.x + ad[0]));
    m[1] = fmaxf(m[1], leaky(asv.y + ad[1]));
    m[2] = fmaxf(m[2], leaky(asv.z + ad[2]));
    m[3] = fmaxf(m[3], leaky(asv.w + ad[3]));
  }
#pragma unroll
  for (int j = 0; j < 4; ++j) m[j] = wmax(m[j]);
  // pass 2: per-head sum of exp
  float d[4] = {0.f, 0.f, 0.f, 0.f};
  for (int e = beg + lane; e < end; e += 64) {
    int s = csr[e];
    const float4 asv = *(const float4*)(a_s + s * HEADS);
    d[0] += expf(leaky(asv.x + ad[0]) - m[0]);
    d[1] += expf(leaky(asv.y + ad[1]) - m[1]);
    d[2] += expf(leaky(asv.z + ad[2]) - m[2]);
    d[3] += expf(leaky(asv.w + ad[3]) - m[3]);
  }
#pragma unroll
  for (int j = 0; j < 4; ++j) d[j] = 1.f / wsum(d[j]);
  // per-lane head: lane's 8 channels are head hh = lane>>4, c = (lane&15)*8 + j
  const int hh = lane >> 4;
  const int c0 = (lane & 15) * 8;
  const float mh = m[hh];
  const float rh = d[hh];
  const float adh = ad[hh];
  float acc[8] = {};
  // pass 3: weighted gather (whole wave per edge; coalesced float4 x2)
  for (int e = beg; e < end; ++e) {
    int s = csr[e];
    float asv = a_s[s * HEADS + hh];
    float al = expf(leaky(asv + adh) - mh) * rh;
    const float* row = xh + (size_t)s * (HEADS * HID) + lane * 8;
    float4 r0 = *(const float4*)(row);
    float4 r1 = *(const float4*)(row + 4);
    acc[0] = fmaf(al, r0.x, acc[0]);
    acc[1] = fmaf(al, r0.y, acc[1]);
    acc[2] = fmaf(al, r0.z, acc[2]);
    acc[3] = fmaf(al, r0.w, acc[3]);
    acc[4] = fmaf(al, r1.x, acc[4]);
    acc[5] = fmaf(al, r1.y, acc[5]);
    acc[6] = fmaf(al, r1.z, acc[6]);
    acc[7] = fmaf(al, r1.w, acc[7]);
  }
  // head mean: channels replicated across 4 16-lane groups
#pragma unroll
  for (int j = 0; j < 8; ++j) {
    acc[j] += __shfl_xor(acc[j], 16, 64);
    acc[j] += __shfl_xor(acc[j], 32, 64);
    acc[j] *= 0.25f;
  }
  float v[8];
#pragma unroll
  for (int j = 0; j < 8; ++j) v[j] = acc[j] + bias[c0 + j];
  // LayerNorm over 128 channels (each channel replicated 4x across wave)
  float s8 = 0.f;
#pragma unroll
  for (int j = 0; j < 8; ++j) s8 += v[j];
  float mu = wsum(s8) * (1.f / 512.f);
  float q = 0.f;
#pragma unroll
  for (int j = 0; j < 8; ++j) q += (v[j] - mu) * (v[j] - mu);
  float var = wsum(q) * (1.f / 512.f);
  float rstd = rsqrtf(var + LN_EPS);
  float* hr = h + (size_t)n * HID;
  if (lane < 16) {
    float y[8];
#pragma unroll
    for (int j = 0; j < 8; ++j) {
      float t = (v[j] - mu) * rstd * gamma[c0 + j] + beta[c0 + j];
      t = fmaxf(t, 0.f);
      y[j] = t + hr[c0 + j];
    }
    *(float4*)(hr + c0) = make_float4(y[0], y[1], y[2], y[3]);
    *(float4*)(hr + c0 + 4) = make_float4(y[4], y[5], y[6], y[7]);
  }
}

// ---------------- GCN head ----------------
__global__ __launch_bounds__(256) void k_xw(const float* __restrict__ h,
                                            const float* __restrict__ W,
                                            float* __restrict__ xw, int N) {
  int lane = threadIdx.x & 63;
  int n = blockIdx.x * 4 + (threadIdx.x >> 6);
  if (n >= N) return;
  const float* hr = h + (size_t)n * HID;
  float v = hr[lane] * W[lane] + hr[64 + lane] * W[64 + lane];
  v = wsum(v);
  if (lane == 0) xw[n] = v;
}

__global__ __launch_bounds__(256) void k_gcn(const int* __restrict__ rowptr,
                                             const int* __restrict__ csr,
                                             const float* __restrict__ xw,
                                             const float* __restrict__ dinv,
                                             const float* __restrict__ gcn_b,
                                             float* __restrict__ out, int N) {
  int n = blockIdx.x * blockDim.x + threadIdx.x;
  if (n >= N) return;
  float acc = 0.f;
  int beg = rowptr[n], end = rowptr[n + 1];
  for (int e = beg; e < end; ++e) {
    int s = csr[e];
    acc += xw[s] * dinv[s];
  }
  float z = acc * dinv[n] + gcn_b[0];
  out[n] = 1.f / (1.f + expf(-z));
}

extern "C" void kernel_launch(void* const* d_in, const int* in_sizes, int n_in,
                              void* d_out, int out_size, void* d_ws, size_t ws_size,
                              hipStream_t stream) {
  const float* x = (const float*)d_in[0];
  const int* ei = (const int*)d_in[1];
  const float* proj_W = (const float*)d_in[2];
  const float* proj_b = (const float*)d_in[3];
  const float* gat_W = (const float*)d_in[4];
  const float* gat_as = (const float*)d_in[5];
  const float* gat_ad = (const float*)d_in[6];
  const float* gat_bias = (const float*)d_in[7];
  const float* ln_g = (const float*)d_in[8];
  const float* ln_b = (const float*)d_in[9];
  const float* gcn_W = (const float*)d_in[10];
  const float* gcn_b = (const float*)d_in[11];
  float* out = (float*)d_out;

  const int N = in_sizes[0] / INDIM;  // 40000
  const int E = in_sizes[1] / 2;      // 320000
  const int TOT = E + N;

  // workspace carve-up
  size_t off = 0;
  auto alloc = [&](size_t bytes) {
    void* p = (char*)d_ws + off;
    off += (bytes + 255) & ~(size_t)255;
    return p;
  };
  float* h = (float*)alloc((size_t)N * HID * 4);
  float* xh = (float*)alloc((size_t)N * HEADS * HID * 4);
  float* a_s = (float*)alloc((size_t)N * HEADS * 4);
  float* a_d = (float*)alloc((size_t)N * HEADS * 4);
  int* deg = (int*)alloc((size_t)N * 4);
  int* rowptr = (int*)alloc((size_t)(N + 1) * 4);
  int* cursor = (int*)alloc((size_t)N * 4);
  int* csr = (int*)alloc((size_t)TOT * 4);
  int* bsums = (int*)alloc(1024);
  float* dinv = (float*)alloc((size_t)N * 4);
  float* xw = (float*)alloc((size_t)N * 4);
  (void)ws_size;

  const int NBLK = (N + 255) / 256;        // 157
  const int EBLK = (TOT + 255) / 256;      // 1407
  const int WBLK = (N + 3) / 4;            // 10000 (4 waves/block, 1 node/wave)

  // CSR build
  hipMemsetAsync(deg, 0, (size_t)N * 4, stream);
  k_deg<<<EBLK, 256, 0, stream>>>(ei, E, N, deg);
  k_scan1<<<NBLK, 256, 0, stream>>>(deg, N, bsums);
  k_scan2<<<1, 1, 0, stream>>>(bsums, NBLK, rowptr, N);
  k_scan3<<<NBLK, 256, 0, stream>>>(deg, N, bsums, rowptr, cursor);
  k_fill<<<EBLK, 256, 0, stream>>>(ei, E, N, cursor, csr);
  k_dinv<<<NBLK, 256, 0, stream>>>(deg, N, dinv);

  // projection: h = x @ proj_W + proj_b
  k_gemm<INDIM, true><<<dim3((N + 63) / 64, HID / 64), 256, 0, stream>>>(
      x, proj_W, proj_b, h, N, HID);

  for (int i = 0; i < NGAT; ++i) {
    const float* Wi = gat_W + (size_t)i * HID * HEADS * HID;
    k_gemm<HID, false><<<dim3((N + 63) / 64, (HEADS * HID) / 64), 256, 0, stream>>>(
        h, Wi, nullptr, xh, N, HEADS * HID);
    k_att<<<WBLK, 256, 0, stream>>>(xh, gat_as + (size_t)i * HEADS * HID,
                                    gat_ad + (size_t)i * HEADS * HID, a_s, a_d, N);
    k_gat_agg<<<WBLK, 256, 0, stream>>>(rowptr, csr, xh, a_s, a_d, h,
                                        gat_bias + (size_t)i * HID,
                                        ln_g + (size_t)i * HID,
                                        ln_b + (size_t)i * HID, N);
  }

  // GCN head
  k_xw<<<WBLK, 256, 0, stream>>>(h, gcn_W, xw, N);
  k_gcn<<<NBLK, 256, 0, stream>>>(rowptr, csr, xw, dinv, gcn_b, out, N);
}

// Round 2
// 496.533 us; speedup vs baseline: 1.4582x; 1.4582x over previous
//
#include <hip/hip_runtime.h>
#include <math.h>

#define INDIM 256
#define HID 128
#define HEADS 4
#define NGAT 3
#define LN_EPS 1e-5f
#define SLOPE 0.2f
#define MPAD 40064  // 313 * 128

typedef __attribute__((ext_vector_type(8))) short short8;
typedef __attribute__((ext_vector_type(4))) float f32x4;

__device__ inline float wsum(float v) {
#pragma unroll
  for (int m = 1; m < 64; m <<= 1) v += __shfl_xor(v, m, 64);
  return v;
}
__device__ inline float wmax(float v) {
#pragma unroll
  for (int m = 1; m < 64; m <<= 1) v = fmaxf(v, __shfl_xor(v, m, 64));
  return v;
}
__device__ inline float leaky(float v) { return v > 0.f ? v : SLOPE * v; }

__device__ inline unsigned short f2b(float f) {
  unsigned u = __float_as_uint(f);
  unsigned r = (u + 0x7FFFu + ((u >> 16) & 1u)) >> 16;
  return (unsigned short)r;
}
__device__ inline void unp8(const uint4 v, float f[8]) {
  f[0] = __uint_as_float(v.x << 16);
  f[1] = __uint_as_float(v.x & 0xFFFF0000u);
  f[2] = __uint_as_float(v.y << 16);
  f[3] = __uint_as_float(v.y & 0xFFFF0000u);
  f[4] = __uint_as_float(v.z << 16);
  f[5] = __uint_as_float(v.z & 0xFFFF0000u);
  f[6] = __uint_as_float(v.w << 16);
  f[7] = __uint_as_float(v.w & 0xFFFF0000u);
}

// ---------------- CSR construction ----------------
__global__ void k_deg(const int* __restrict__ ei, int E, int N, int* __restrict__ deg) {
  int e = blockIdx.x * blockDim.x + threadIdx.x;
  if (e >= E + N) return;
  int dst = (e < E) ? ei[E + e] : (e - E);
  atomicAdd(&deg[dst], 1);
}

__global__ void k_scan1(const int* __restrict__ deg, int N, int* __restrict__ bsums) {
  __shared__ int s[256];
  int gid = blockIdx.x * 256 + threadIdx.x;
  s[threadIdx.x] = (gid < N) ? deg[gid] : 0;
  __syncthreads();
  for (int off = 128; off > 0; off >>= 1) {
    if (threadIdx.x < off) s[threadIdx.x] += s[threadIdx.x + off];
    __syncthreads();
  }
  if (threadIdx.x == 0) bsums[blockIdx.x] = s[0];
}

__global__ void k_scan2(int* __restrict__ bsums, int nblk, int* __restrict__ rowptr, int N) {
  if (threadIdx.x == 0 && blockIdx.x == 0) {
    int run = 0;
    for (int i = 0; i < nblk; ++i) { int t = bsums[i]; bsums[i] = run; run += t; }
    rowptr[N] = run;
  }
}

__global__ void k_scan3(const int* __restrict__ deg, int N, const int* __restrict__ bsums,
                        int* __restrict__ rowptr, int* __restrict__ cursor) {
  __shared__ int s[256];
  int gid = blockIdx.x * 256 + threadIdx.x;
  int v = (gid < N) ? deg[gid] : 0;
  s[threadIdx.x] = v;
  __syncthreads();
  for (int off = 1; off < 256; off <<= 1) {
    int t = (threadIdx.x >= off) ? s[threadIdx.x - off] : 0;
    __syncthreads();
    s[threadIdx.x] += t;
    __syncthreads();
  }
  if (gid < N) {
    int ex = bsums[blockIdx.x] + s[threadIdx.x] - v;
    rowptr[gid] = ex;
    cursor[gid] = ex;
  }
}

__global__ void k_fill(const int* __restrict__ ei, int E, int N,
                       int* __restrict__ cursor, int* __restrict__ csr) {
  int e = blockIdx.x * blockDim.x + threadIdx.x;
  if (e >= E + N) return;
  int src, dst;
  if (e < E) { src = ei[e]; dst = ei[E + e]; } else { src = dst = e - E; }
  int pos = atomicAdd(&cursor[dst], 1);
  csr[pos] = src;
}

__global__ void k_dinv(const int* __restrict__ deg, int N, float* __restrict__ dinv) {
  int n = blockIdx.x * blockDim.x + threadIdx.x;
  if (n < N) dinv[n] = rsqrtf((float)deg[n]);
}

// ---------------- conversions ----------------
// fp32 -> bf16, 4 elems/thread, zero-fills the padded tail rows
__global__ void k_f2b(const float* __restrict__ in, unsigned short* __restrict__ out,
                      int n_valid, int n_total) {
  int base = (blockIdx.x * 256 + threadIdx.x) * 4;
  if (base >= n_total) return;
  float4 v = (base < n_valid) ? *(const float4*)(in + base) : make_float4(0.f, 0.f, 0.f, 0.f);
  ushort2 lo = make_ushort2(f2b(v.x), f2b(v.y));
  ushort2 hi = make_ushort2(f2b(v.z), f2b(v.w));
  unsigned p0 = (unsigned)lo.x | ((unsigned)lo.y << 16);
  unsigned p1 = (unsigned)hi.x | ((unsigned)hi.y << 16);
  *(uint2*)(out + base) = make_uint2(p0, p1);
}

// W [K][Nc] fp32 -> Wt [Nc][K] bf16
__global__ void k_wt(const float* __restrict__ W, unsigned short* __restrict__ Wt,
                     int K, int Nc) {
  int idx = blockIdx.x * 256 + threadIdx.x;
  if (idx >= K * Nc) return;
  int k = idx / Nc, n = idx % Nc;
  Wt[n * K + k] = f2b(W[idx]);
}

// ---------------- bf16 MFMA GEMM: C[M,Nc] = A[MPAD,K] @ Bt[Nc,K]^T ----------------
// A row-major bf16, Bt row-major bf16 (i.e. B transposed). 128x128 block tile,
// 4 waves of 64x64. Fragments loaded straight from global (K<=256, L2-resident B).
template <int K, bool F32OUT>
__global__ __launch_bounds__(256) void k_mm(const unsigned short* __restrict__ A,
                                            const unsigned short* __restrict__ Bt,
                                            const float* __restrict__ bias,
                                            float* __restrict__ Cf,
                                            unsigned short* __restrict__ Cb, int Nc) {
  const int wid = threadIdx.x >> 6;
  const int lane = threadIdx.x & 63;
  const int bm = blockIdx.x * 128;
  const int bn = blockIdx.y * 128;
  const int wr = (wid >> 1) * 64;
  const int wc = (wid & 1) * 64;
  const int l15 = lane & 15;
  const int lk = (lane >> 4) * 8;
  f32x4 acc[4][4] = {};
  const unsigned short* Ap = A + (size_t)(bm + wr + l15) * K + lk;
  const unsigned short* Bp = Bt + (size_t)(bn + wc + l15) * K + lk;
  for (int k0 = 0; k0 < K; k0 += 32) {
    short8 af[4], bfr[4];
#pragma unroll
    for (int i = 0; i < 4; ++i) af[i] = *(const short8*)(Ap + (size_t)i * 16 * K + k0);
#pragma unroll
    for (int i = 0; i < 4; ++i) bfr[i] = *(const short8*)(Bp + (size_t)i * 16 * K + k0);
#pragma unroll
    for (int mi = 0; mi < 4; ++mi)
#pragma unroll
      for (int ni = 0; ni < 4; ++ni)
        acc[mi][ni] = __builtin_amdgcn_mfma_f32_16x16x32_bf16(af[mi], bfr[ni], acc[mi][ni], 0, 0, 0);
  }
  const int rbase = bm + wr + (lane >> 4) * 4;
#pragma unroll
  for (int mi = 0; mi < 4; ++mi) {
#pragma unroll
    for (int ni = 0; ni < 4; ++ni) {
      const int col = bn + wc + ni * 16 + l15;
      const float bv = bias ? bias[col] : 0.f;
#pragma unroll
      for (int r = 0; r < 4; ++r) {
        const int row = rbase + mi * 16 + r;
        const float v = acc[mi][ni][r] + bv;
        if (F32OUT) Cf[(size_t)row * Nc + col] = v;
        Cb[(size_t)row * Nc + col] = f2b(v);
      }
    }
  }
}

// ---------------- attention logits a_s/a_d: [N, HEADS] (bf16 xh) ----------------
__global__ __launch_bounds__(256) void k_att(const unsigned short* __restrict__ xh,
                                             const float* __restrict__ atts,
                                             const float* __restrict__ attd,
                                             float* __restrict__ a_s,
                                             float* __restrict__ a_d, int N) {
  int lane = threadIdx.x & 63;
  int n = blockIdx.x * 4 + (threadIdx.x >> 6);
  if (n >= N) return;
  int base = lane * 8;
  uint4 rv = *(const uint4*)(xh + (size_t)n * (HEADS * HID) + base);
  float f[8];
  unp8(rv, f);
  float4 s0 = *(const float4*)(atts + base);
  float4 s1 = *(const float4*)(atts + base + 4);
  float4 d0 = *(const float4*)(attd + base);
  float4 d1 = *(const float4*)(attd + base + 4);
  float ss = f[0] * s0.x + f[1] * s0.y + f[2] * s0.z + f[3] * s0.w +
             f[4] * s1.x + f[5] * s1.y + f[6] * s1.z + f[7] * s1.w;
  float sd = f[0] * d0.x + f[1] * d0.y + f[2] * d0.z + f[3] * d0.w +
             f[4] * d1.x + f[5] * d1.y + f[6] * d1.z + f[7] * d1.w;
#pragma unroll
  for (int m = 1; m < 16; m <<= 1) {
    ss += __shfl_xor(ss, m, 64);
    sd += __shfl_xor(sd, m, 64);
  }
  if ((lane & 15) == 0) {
    int h = lane >> 4;
    a_s[n * HEADS + h] = ss;
    a_d[n * HEADS + h] = sd;
  }
}

// ---------------- GAT aggregation + head-mean + bias + LN + ReLU + residual ----------------
__global__ __launch_bounds__(256) void k_gat_agg(
    const int* __restrict__ rowptr, const int* __restrict__ csr,
    const unsigned short* __restrict__ xh, const float* __restrict__ a_s,
    const float* __restrict__ a_d, float* __restrict__ h,
    unsigned short* __restrict__ hb, const float* __restrict__ bias,
    const float* __restrict__ gamma, const float* __restrict__ beta, int N) {
  int lane = threadIdx.x & 63;
  int n = blockIdx.x * 4 + (threadIdx.x >> 6);
  if (n >= N) return;
  int beg = rowptr[n], end = rowptr[n + 1];
  const float4 adv = *(const float4*)(a_d + n * HEADS);
  float ad[4] = {adv.x, adv.y, adv.z, adv.w};
  float m[4] = {-1e30f, -1e30f, -1e30f, -1e30f};
  for (int e = beg + lane; e < end; e += 64) {
    int s = csr[e];
    const float4 asv = *(const float4*)(a_s + s * HEADS);
    m[0] = fmaxf(m[0], leaky(asv.x + ad[0]));
    m[1] = fmaxf(m[1], leaky(asv.y + ad[1]));
    m[2] = fmaxf(m[2], leaky(asv.z + ad[2]));
    m[3] = fmaxf(m[3], leaky(asv.w + ad[3]));
  }
#pragma unroll
  for (int j = 0; j < 4; ++j) m[j] = wmax(m[j]);
  float d[4] = {0.f, 0.f, 0.f, 0.f};
  for (int e = beg + lane; e < end; e += 64) {
    int s = csr[e];
    const float4 asv = *(const float4*)(a_s + s * HEADS);
    d[0] += expf(leaky(asv.x + ad[0]) - m[0]);
    d[1] += expf(leaky(asv.y + ad[1]) - m[1]);
    d[2] += expf(leaky(asv.z + ad[2]) - m[2]);
    d[3] += expf(leaky(asv.w + ad[3]) - m[3]);
  }
#pragma unroll
  for (int j = 0; j < 4; ++j) d[j] = 1.f / wsum(d[j]);
  const int hh = lane >> 4;
  const int c0 = (lane & 15) * 8;
  const float mh = m[hh];
  const float rh = d[hh];
  const float adh = ad[hh];
  float acc[8] = {};
  // pass 3: weighted gather, bf16 rows, 2-edge unroll for MLP
  int e = beg;
  for (; e + 1 < end; e += 2) {
    int s0 = csr[e], s1 = csr[e + 1];
    float as0 = a_s[s0 * HEADS + hh];
    float as1 = a_s[s1 * HEADS + hh];
    uint4 r0 = *(const uint4*)(xh + (size_t)s0 * (HEADS * HID) + lane * 8);
    uint4 r1 = *(const uint4*)(xh + (size_t)s1 * (HEADS * HID) + lane * 8);
    float al0 = expf(leaky(as0 + adh) - mh) * rh;
    float al1 = expf(leaky(as1 + adh) - mh) * rh;
    float f0[8], f1[8];
    unp8(r0, f0);
    unp8(r1, f1);
#pragma unroll
    for (int j = 0; j < 8; ++j) acc[j] = fmaf(al0, f0[j], acc[j]);
#pragma unroll
    for (int j = 0; j < 8; ++j) acc[j] = fmaf(al1, f1[j], acc[j]);
  }
  if (e < end) {
    int s0 = csr[e];
    float as0 = a_s[s0 * HEADS + hh];
    uint4 r0 = *(const uint4*)(xh + (size_t)s0 * (HEADS * HID) + lane * 8);
    float al0 = expf(leaky(as0 + adh) - mh) * rh;
    float f0[8];
    unp8(r0, f0);
#pragma unroll
    for (int j = 0; j < 8; ++j) acc[j] = fmaf(al0, f0[j], acc[j]);
  }
  // head mean across the 4 16-lane groups
#pragma unroll
  for (int j = 0; j < 8; ++j) {
    acc[j] += __shfl_xor(acc[j], 16, 64);
    acc[j] += __shfl_xor(acc[j], 32, 64);
    acc[j] *= 0.25f;
  }
  float v[8];
#pragma unroll
  for (int j = 0; j < 8; ++j) v[j] = acc[j] + bias[c0 + j];
  float s8 = 0.f;
#pragma unroll
  for (int j = 0; j < 8; ++j) s8 += v[j];
  float mu = wsum(s8) * (1.f / 512.f);
  float q = 0.f;
#pragma unroll
  for (int j = 0; j < 8; ++j) q += (v[j] - mu) * (v[j] - mu);
  float var = wsum(q) * (1.f / 512.f);
  float rstd = rsqrtf(var + LN_EPS);
  float* hr = h + (size_t)n * HID;
  if (lane < 16) {
    float y[8];
#pragma unroll
    for (int j = 0; j < 8; ++j) {
      float t = (v[j] - mu) * rstd * gamma[c0 + j] + beta[c0 + j];
      t = fmaxf(t, 0.f);
      y[j] = t + hr[c0 + j];
    }
    *(float4*)(hr + c0) = make_float4(y[0], y[1], y[2], y[3]);
    *(float4*)(hr + c0 + 4) = make_float4(y[4], y[5], y[6], y[7]);
    unsigned p0 = (unsigned)f2b(y[0]) | ((unsigned)f2b(y[1]) << 16);
    unsigned p1 = (unsigned)f2b(y[2]) | ((unsigned)f2b(y[3]) << 16);
    unsigned p2 = (unsigned)f2b(y[4]) | ((unsigned)f2b(y[5]) << 16);
    unsigned p3 = (unsigned)f2b(y[6]) | ((unsigned)f2b(y[7]) << 16);
    *(uint4*)(hb + (size_t)n * HID + c0) = make_uint4(p0, p1, p2, p3);
  }
}

// ---------------- GCN head ----------------
__global__ __launch_bounds__(256) void k_xw(const float* __restrict__ h,
                                            const float* __restrict__ W,
                                            float* __restrict__ xw, int N) {
  int lane = threadIdx.x & 63;
  int n = blockIdx.x * 4 + (threadIdx.x >> 6);
  if (n >= N) return;
  const float* hr = h + (size_t)n * HID;
  float v = hr[lane] * W[lane] + hr[64 + lane] * W[64 + lane];
  v = wsum(v);
  if (lane == 0) xw[n] = v;
}

__global__ __launch_bounds__(256) void k_gcn(const int* __restrict__ rowptr,
                                             const int* __restrict__ csr,
                                             const float* __restrict__ xw,
                                             const float* __restrict__ dinv,
                                             const float* __restrict__ gcn_b,
                                             float* __restrict__ out, int N) {
  int n = blockIdx.x * blockDim.x + threadIdx.x;
  if (n >= N) return;
  float acc = 0.f;
  int beg = rowptr[n], end = rowptr[n + 1];
  for (int e = beg; e < end; ++e) {
    int s = csr[e];
    acc += xw[s] * dinv[s];
  }
  float z = acc * dinv[n] + gcn_b[0];
  out[n] = 1.f / (1.f + expf(-z));
}

extern "C" void kernel_launch(void* const* d_in, const int* in_sizes, int n_in,
                              void* d_out, int out_size, void* d_ws, size_t ws_size,
                              hipStream_t stream) {
  const float* x = (const float*)d_in[0];
  const int* ei = (const int*)d_in[1];
  const float* proj_W = (const float*)d_in[2];
  const float* proj_b = (const float*)d_in[3];
  const float* gat_W = (const float*)d_in[4];
  const float* gat_as = (const float*)d_in[5];
  const float* gat_ad = (const float*)d_in[6];
  const float* gat_bias = (const float*)d_in[7];
  const float* ln_g = (const float*)d_in[8];
  const float* ln_b = (const float*)d_in[9];
  const float* gcn_W = (const float*)d_in[10];
  const float* gcn_b = (const float*)d_in[11];
  float* out = (float*)d_out;

  const int N = in_sizes[0] / INDIM;  // 40000
  const int E = in_sizes[1] / 2;      // 320000
  const int TOT = E + N;

  size_t off = 0;
  auto alloc = [&](size_t bytes) {
    void* p = (char*)d_ws + off;
    off += (bytes + 255) & ~(size_t)255;
    return p;
  };
  float* h = (float*)alloc((size_t)MPAD * HID * 4);
  unsigned short* hb = (unsigned short*)alloc((size_t)MPAD * HID * 2);
  unsigned short* xhb = (unsigned short*)alloc((size_t)MPAD * HEADS * HID * 2);
  unsigned short* xb = (unsigned short*)alloc((size_t)MPAD * INDIM * 2);
  unsigned short* WtP = (unsigned short*)alloc((size_t)HID * INDIM * 2);
  unsigned short* WtG = (unsigned short*)alloc((size_t)NGAT * (HEADS * HID) * HID * 2);
  float* a_s = (float*)alloc((size_t)N * HEADS * 4);
  float* a_d = (float*)alloc((size_t)N * HEADS * 4);
  int* deg = (int*)alloc((size_t)N * 4);
  int* rowptr = (int*)alloc((size_t)(N + 1) * 4);
  int* cursor = (int*)alloc((size_t)N * 4);
  int* csr = (int*)alloc((size_t)TOT * 4);
  int* bsums = (int*)alloc(1024);
  float* dinv = (float*)alloc((size_t)N * 4);
  float* xw = (float*)alloc((size_t)N * 4);
  (void)ws_size;

  const int NBLK = (N + 255) / 256;
  const int EBLK = (TOT + 255) / 256;
  const int WBLK = (N + 3) / 4;

  // CSR build
  hipMemsetAsync(deg, 0, (size_t)N * 4, stream);
  k_deg<<<EBLK, 256, 0, stream>>>(ei, E, N, deg);
  k_scan1<<<NBLK, 256, 0, stream>>>(deg, N, bsums);
  k_scan2<<<1, 1, 0, stream>>>(bsums, NBLK, rowptr, N);
  k_scan3<<<NBLK, 256, 0, stream>>>(deg, N, bsums, rowptr, cursor);
  k_fill<<<EBLK, 256, 0, stream>>>(ei, E, N, cursor, csr);
  k_dinv<<<NBLK, 256, 0, stream>>>(deg, N, dinv);

  // conversions: x -> bf16 (zero pad rows), weights -> transposed bf16
  k_f2b<<<(MPAD * INDIM / 4 + 255) / 256, 256, 0, stream>>>(x, xb, N * INDIM, MPAD * INDIM);
  k_wt<<<(INDIM * HID + 255) / 256, 256, 0, stream>>>(proj_W, WtP, INDIM, HID);
  for (int i = 0; i < NGAT; ++i)
    k_wt<<<(HID * HEADS * HID + 255) / 256, 256, 0, stream>>>(
        gat_W + (size_t)i * HID * HEADS * HID, WtG + (size_t)i * (HEADS * HID) * HID,
        HID, HEADS * HID);

  // projection: h = x @ proj_W + proj_b (fp32 + bf16 copies)
  k_mm<INDIM, true><<<dim3(MPAD / 128, 1), 256, 0, stream>>>(xb, WtP, proj_b, h, hb, HID);

  for (int i = 0; i < NGAT; ++i) {
    k_mm<HID, false><<<dim3(MPAD / 128, (HEADS * HID) / 128), 256, 0, stream>>>(
        hb, WtG + (size_t)i * (HEADS * HID) * HID, nullptr, nullptr, xhb, HEADS * HID);
    k_att<<<WBLK, 256, 0, stream>>>(xhb, gat_as + (size_t)i * HEADS * HID,
                                    gat_ad + (size_t)i * HEADS * HID, a_s, a_d, N);
    k_gat_agg<<<WBLK, 256, 0, stream>>>(rowptr, csr, xhb, a_s, a_d, h, hb,
                                        gat_bias + (size_t)i * HID,
                                        ln_g + (size_t)i * HID,
                                        ln_b + (size_t)i * HID, N);
  }

  // GCN head
  k_xw<<<WBLK, 256, 0, stream>>>(h, gcn_W, xw, N);
  k_gcn<<<NBLK, 256, 0, stream>>>(rowptr, csr, xw, dinv, gcn_b, out, N);
}

// Round 3
// 456.051 us; speedup vs baseline: 1.5877x; 1.0888x over previous
//
#include <hip/hip_runtime.h>
#include <math.h>

#define INDIM 256
#define HID 128
#define HEADS 4
#define NGAT 3
#define LN_EPS 1e-5f
#define SLOPE 0.2f
#define MPAD 40064  // 313 * 128
#define LOG2E 1.4426950408889634f

typedef __attribute__((ext_vector_type(8))) short short8;
typedef __attribute__((ext_vector_type(4))) float f32x4;

__device__ inline float wsum(float v) {
#pragma unroll
  for (int m = 1; m < 64; m <<= 1) v += __shfl_xor(v, m, 64);
  return v;
}
__device__ inline float wmax(float v) {
#pragma unroll
  for (int m = 1; m < 64; m <<= 1) v = fmaxf(v, __shfl_xor(v, m, 64));
  return v;
}
// leaky_relu then scale to exp2 domain
__device__ inline float lk2(float v) { return fmaxf(v, SLOPE * v) * LOG2E; }
// static-select from 4-elem register array (avoid dynamic indexing -> scratch)
__device__ inline float sel4(const float a[4], int i) {
  float lo = (i & 1) ? a[1] : a[0];
  float hi = (i & 1) ? a[3] : a[2];
  return (i & 2) ? hi : lo;
}

__device__ inline unsigned short f2b(float f) {
  unsigned u = __float_as_uint(f);
  unsigned r = (u + 0x7FFFu + ((u >> 16) & 1u)) >> 16;
  return (unsigned short)r;
}
__device__ inline void unp8(const uint4 v, float f[8]) {
  f[0] = __uint_as_float(v.x << 16);
  f[1] = __uint_as_float(v.x & 0xFFFF0000u);
  f[2] = __uint_as_float(v.y << 16);
  f[3] = __uint_as_float(v.y & 0xFFFF0000u);
  f[4] = __uint_as_float(v.z << 16);
  f[5] = __uint_as_float(v.z & 0xFFFF0000u);
  f[6] = __uint_as_float(v.w << 16);
  f[7] = __uint_as_float(v.w & 0xFFFF0000u);
}

// ---------------- CSR construction ----------------
__global__ void k_deg(const int* __restrict__ ei, int E, int N, int* __restrict__ deg) {
  int e = blockIdx.x * blockDim.x + threadIdx.x;
  if (e >= E + N) return;
  int dst = (e < E) ? ei[E + e] : (e - E);
  atomicAdd(&deg[dst], 1);
}

__global__ void k_scan1(const int* __restrict__ deg, int N, int* __restrict__ bsums) {
  __shared__ int s[256];
  int gid = blockIdx.x * 256 + threadIdx.x;
  s[threadIdx.x] = (gid < N) ? deg[gid] : 0;
  __syncthreads();
  for (int off = 128; off > 0; off >>= 1) {
    if (threadIdx.x < off) s[threadIdx.x] += s[threadIdx.x + off];
    __syncthreads();
  }
  if (threadIdx.x == 0) bsums[blockIdx.x] = s[0];
}

__global__ void k_scan2(int* __restrict__ bsums, int nblk, int* __restrict__ rowptr, int N) {
  if (threadIdx.x == 0 && blockIdx.x == 0) {
    int run = 0;
    for (int i = 0; i < nblk; ++i) { int t = bsums[i]; bsums[i] = run; run += t; }
    rowptr[N] = run;
  }
}

__global__ void k_scan3(const int* __restrict__ deg, int N, const int* __restrict__ bsums,
                        int* __restrict__ rowptr, int* __restrict__ cursor,
                        float* __restrict__ dinv) {
  __shared__ int s[256];
  int gid = blockIdx.x * 256 + threadIdx.x;
  int v = (gid < N) ? deg[gid] : 0;
  s[threadIdx.x] = v;
  __syncthreads();
  for (int off = 1; off < 256; off <<= 1) {
    int t = (threadIdx.x >= off) ? s[threadIdx.x - off] : 0;
    __syncthreads();
    s[threadIdx.x] += t;
    __syncthreads();
  }
  if (gid < N) {
    int ex = bsums[blockIdx.x] + s[threadIdx.x] - v;
    rowptr[gid] = ex;
    cursor[gid] = ex;
    dinv[gid] = rsqrtf((float)v);
  }
}

__global__ void k_fill(const int* __restrict__ ei, int E, int N,
                       int* __restrict__ cursor, int* __restrict__ csr) {
  int e = blockIdx.x * blockDim.x + threadIdx.x;
  if (e >= E + N) return;
  int src, dst;
  if (e < E) { src = ei[e]; dst = ei[E + e]; } else { src = dst = e - E; }
  int pos = atomicAdd(&cursor[dst], 1);
  csr[pos] = src;
}

// ---------------- weight transposes (fp32 -> bf16) ----------------
// proj_W [INDIM][HID] -> WtP [HID][INDIM]
__global__ void k_wt(const float* __restrict__ W, unsigned short* __restrict__ Wt,
                     int K, int Nc) {
  int idx = blockIdx.x * 256 + threadIdx.x;
  if (idx >= K * Nc) return;
  int k = idx / Nc, n = idx % Nc;
  Wt[n * K + k] = f2b(W[idx]);
}
// gat_W [NGAT][HID][512] -> WtG [NGAT][512][HID]
__global__ void k_wt3(const float* __restrict__ W, unsigned short* __restrict__ Wt) {
  int idx = blockIdx.x * 256 + threadIdx.x;
  if (idx >= NGAT * HID * HEADS * HID) return;
  int l = idx / (HID * HEADS * HID);
  int rem = idx - l * HID * HEADS * HID;
  int k = rem / (HEADS * HID);
  int n = rem % (HEADS * HID);
  Wt[(size_t)l * (HEADS * HID) * HID + (size_t)n * HID + k] = f2b(W[idx]);
}

// ---------------- bf16 MFMA GEMM (+ optional fused attention logits) ----------------
// C[M,Nc] = A @ Bt^T. A: fp32 (AF32, bounds-guarded to Mreal) or bf16 [MPAD,K].
// Bt row-major bf16 [Nc][K]. 128x128 tile, 4 waves of 64x64.
// ATT: each bn-block covers one head's 128 channels; computes
// a_s[row,h] = sum_c C[row, bn+c]*atts[bn+c] (same for a_d) via shfl+LDS reduce.
template <int K, bool AF32, bool ATT, bool F32OUT>
__global__ __launch_bounds__(256) void k_mm(
    const void* __restrict__ Avoid, const unsigned short* __restrict__ Bt,
    const float* __restrict__ bias, const float* __restrict__ atts,
    const float* __restrict__ attd, float* __restrict__ a_s, float* __restrict__ a_d,
    float* __restrict__ Cf, unsigned short* __restrict__ Cb, int Nc, int Mreal) {
  __shared__ float sS[2][128];
  __shared__ float sD[2][128];
  const int wid = threadIdx.x >> 6;
  const int lane = threadIdx.x & 63;
  const int bm = blockIdx.x * 128;
  const int bn = blockIdx.y * 128;
  const int wr = (wid >> 1) * 64;
  const int wc = (wid & 1) * 64;
  const int l15 = lane & 15;
  const int lk = (lane >> 4) * 8;
  f32x4 acc[4][4] = {};
  const unsigned short* Ab = (const unsigned short*)Avoid;
  const float* Af = (const float*)Avoid;
  const unsigned short* Bp = Bt + (size_t)(bn + wc + l15) * K + lk;
  for (int k0 = 0; k0 < K; k0 += 32) {
    short8 af[4], bfr[4];
#pragma unroll
    for (int i = 0; i < 4; ++i) {
      const int row = bm + wr + l15 + i * 16;
      if (AF32) {
        if (row < Mreal) {
          const float* ap = Af + (size_t)row * K + lk + k0;
          float4 u = *(const float4*)ap;
          float4 v = *(const float4*)(ap + 4);
          af[i][0] = (short)f2b(u.x); af[i][1] = (short)f2b(u.y);
          af[i][2] = (short)f2b(u.z); af[i][3] = (short)f2b(u.w);
          af[i][4] = (short)f2b(v.x); af[i][5] = (short)f2b(v.y);
          af[i][6] = (short)f2b(v.z); af[i][7] = (short)f2b(v.w);
        } else {
          af[i] = short8{0, 0, 0, 0, 0, 0, 0, 0};
        }
      } else {
        af[i] = *(const short8*)(Ab + (size_t)row * K + lk + k0);
      }
    }
#pragma unroll
    for (int i = 0; i < 4; ++i) bfr[i] = *(const short8*)(Bp + (size_t)i * 16 * K + k0);
#pragma unroll
    for (int mi = 0; mi < 4; ++mi)
#pragma unroll
      for (int ni = 0; ni < 4; ++ni)
        acc[mi][ni] = __builtin_amdgcn_mfma_f32_16x16x32_bf16(af[mi], bfr[ni], acc[mi][ni], 0, 0, 0);
  }
  // C write
  const int rbase = bm + wr + (lane >> 4) * 4;
#pragma unroll
  for (int mi = 0; mi < 4; ++mi) {
#pragma unroll
    for (int ni = 0; ni < 4; ++ni) {
      const int col = bn + wc + ni * 16 + l15;
      const float bv = bias ? bias[col] : 0.f;
#pragma unroll
      for (int r = 0; r < 4; ++r) {
        const int row = rbase + mi * 16 + r;
        const float v = acc[mi][ni][r] + bv;
        if (F32OUT) Cf[(size_t)row * Nc + col] = v;
        Cb[(size_t)row * Nc + col] = f2b(v);
      }
    }
  }
  if (ATT) {
    float ws[4], wd[4];
#pragma unroll
    for (int ni = 0; ni < 4; ++ni) {
      ws[ni] = atts[bn + wc + ni * 16 + l15];
      wd[ni] = attd[bn + wc + ni * 16 + l15];
    }
    float ps = 0.f, pd = 0.f;
#pragma unroll
    for (int mi = 0; mi < 4; ++mi) {
#pragma unroll
      for (int r = 0; r < 4; ++r) {
        float vs = acc[mi][0][r] * ws[0] + acc[mi][1][r] * ws[1] +
                   acc[mi][2][r] * ws[2] + acc[mi][3][r] * ws[3];
        float vd = acc[mi][0][r] * wd[0] + acc[mi][1][r] * wd[1] +
                   acc[mi][2][r] * wd[2] + acc[mi][3][r] * wd[3];
#pragma unroll
        for (int m = 1; m < 16; m <<= 1) {
          vs += __shfl_xor(vs, m, 64);
          vd += __shfl_xor(vd, m, 64);
        }
        if (l15 == mi * 4 + r) { ps = vs; pd = vd; }
      }
    }
    const int rowl = wr + (l15 >> 2) * 16 + (lane >> 4) * 4 + (l15 & 3);
    sS[wid & 1][rowl] = ps;
    sD[wid & 1][rowl] = pd;
    __syncthreads();
    const int tid = threadIdx.x;
    if (tid < 128) {
      const int hh = bn >> 7;
      a_s[(size_t)(bm + tid) * HEADS + hh] = sS[0][tid] + sS[1][tid];
      a_d[(size_t)(bm + tid) * HEADS + hh] = sD[0][tid] + sD[1][tid];
    }
  }
}

// ---------------- GAT aggregation + head-mean + bias + LN + ReLU + residual ----------------
__global__ __launch_bounds__(256) void k_gat_agg(
    const int* __restrict__ rowptr, const int* __restrict__ csr,
    const unsigned short* __restrict__ xh, const float* __restrict__ a_s,
    const float* __restrict__ a_d, float* __restrict__ h,
    unsigned short* __restrict__ hb, const float* __restrict__ bias,
    const float* __restrict__ gamma, const float* __restrict__ beta, int N) {
  int lane = threadIdx.x & 63;
  int n = blockIdx.x * 4 + (threadIdx.x >> 6);
  if (n >= N) return;
  int beg = rowptr[n], end = rowptr[n + 1];
  const float4 adv = *(const float4*)(a_d + (size_t)n * HEADS);
  float ad[4] = {adv.x, adv.y, adv.z, adv.w};
  // pass 1: per-head max of leaky(e)*log2e over incoming edges
  float m[4] = {-1e30f, -1e30f, -1e30f, -1e30f};
  for (int e = beg + lane; e < end; e += 64) {
    int s = csr[e];
    const float4 asv = *(const float4*)(a_s + (size_t)s * HEADS);
    m[0] = fmaxf(m[0], lk2(asv.x + ad[0]));
    m[1] = fmaxf(m[1], lk2(asv.y + ad[1]));
    m[2] = fmaxf(m[2], lk2(asv.z + ad[2]));
    m[3] = fmaxf(m[3], lk2(asv.w + ad[3]));
  }
#pragma unroll
  for (int j = 0; j < 4; ++j) m[j] = wmax(m[j]);
  // pass 2: per-head sum of 2^(L-m)
  float d[4] = {0.f, 0.f, 0.f, 0.f};
  for (int e = beg + lane; e < end; e += 64) {
    int s = csr[e];
    const float4 asv = *(const float4*)(a_s + (size_t)s * HEADS);
    d[0] += exp2f(lk2(asv.x + ad[0]) - m[0]);
    d[1] += exp2f(lk2(asv.y + ad[1]) - m[1]);
    d[2] += exp2f(lk2(asv.z + ad[2]) - m[2]);
    d[3] += exp2f(lk2(asv.w + ad[3]) - m[3]);
  }
#pragma unroll
  for (int j = 0; j < 4; ++j) d[j] = 1.f / wsum(d[j]);
  // per-lane head: lane covers channels lane*8..+7, head hh = lane>>4
  const int hh = lane >> 4;
  const int c0 = (lane & 15) * 8;
  const float mh = sel4(m, hh);
  const float rh = sel4(d, hh);
  const float adh = sel4(ad, hh);
  float acc[8] = {};
  float f[8];
  // pass 3: weighted gather, 4 edges in flight
  int e = beg;
  for (; e + 4 <= end; e += 4) {
    int s0 = csr[e + 0], s1 = csr[e + 1], s2 = csr[e + 2], s3 = csr[e + 3];
    float b0 = a_s[(size_t)s0 * HEADS + hh];
    float b1 = a_s[(size_t)s1 * HEADS + hh];
    float b2 = a_s[(size_t)s2 * HEADS + hh];
    float b3 = a_s[(size_t)s3 * HEADS + hh];
    uint4 r0 = *(const uint4*)(xh + (size_t)s0 * (HEADS * HID) + lane * 8);
    uint4 r1 = *(const uint4*)(xh + (size_t)s1 * (HEADS * HID) + lane * 8);
    uint4 r2 = *(const uint4*)(xh + (size_t)s2 * (HEADS * HID) + lane * 8);
    uint4 r3 = *(const uint4*)(xh + (size_t)s3 * (HEADS * HID) + lane * 8);
    float al0 = exp2f(lk2(b0 + adh) - mh) * rh;
    float al1 = exp2f(lk2(b1 + adh) - mh) * rh;
    float al2 = exp2f(lk2(b2 + adh) - mh) * rh;
    float al3 = exp2f(lk2(b3 + adh) - mh) * rh;
    unp8(r0, f);
#pragma unroll
    for (int j = 0; j < 8; ++j) acc[j] = fmaf(al0, f[j], acc[j]);
    unp8(r1, f);
#pragma unroll
    for (int j = 0; j < 8; ++j) acc[j] = fmaf(al1, f[j], acc[j]);
    unp8(r2, f);
#pragma unroll
    for (int j = 0; j < 8; ++j) acc[j] = fmaf(al2, f[j], acc[j]);
    unp8(r3, f);
#pragma unroll
    for (int j = 0; j < 8; ++j) acc[j] = fmaf(al3, f[j], acc[j]);
  }
  for (; e < end; ++e) {
    int s0 = csr[e];
    float b0 = a_s[(size_t)s0 * HEADS + hh];
    uint4 r0 = *(const uint4*)(xh + (size_t)s0 * (HEADS * HID) + lane * 8);
    float al0 = exp2f(lk2(b0 + adh) - mh) * rh;
    unp8(r0, f);
#pragma unroll
    for (int j = 0; j < 8; ++j) acc[j] = fmaf(al0, f[j], acc[j]);
  }
  // head mean across the 4 16-lane groups
#pragma unroll
  for (int j = 0; j < 8; ++j) {
    acc[j] += __shfl_xor(acc[j], 16, 64);
    acc[j] += __shfl_xor(acc[j], 32, 64);
    acc[j] *= 0.25f;
  }
  float v[8];
#pragma unroll
  for (int j = 0; j < 8; ++j) v[j] = acc[j] + bias[c0 + j];
  float s8 = 0.f;
#pragma unroll
  for (int j = 0; j < 8; ++j) s8 += v[j];
  float mu = wsum(s8) * (1.f / 512.f);
  float q = 0.f;
#pragma unroll
  for (int j = 0; j < 8; ++j) q += (v[j] - mu) * (v[j] - mu);
  float var = wsum(q) * (1.f / 512.f);
  float rstd = rsqrtf(var + LN_EPS);
  float* hr = h + (size_t)n * HID;
  if (lane < 16) {
    float y[8];
#pragma unroll
    for (int j = 0; j < 8; ++j) {
      float t = (v[j] - mu) * rstd * gamma[c0 + j] + beta[c0 + j];
      t = fmaxf(t, 0.f);
      y[j] = t + hr[c0 + j];
    }
    *(float4*)(hr + c0) = make_float4(y[0], y[1], y[2], y[3]);
    *(float4*)(hr + c0 + 4) = make_float4(y[4], y[5], y[6], y[7]);
    unsigned p0 = (unsigned)f2b(y[0]) | ((unsigned)f2b(y[1]) << 16);
    unsigned p1 = (unsigned)f2b(y[2]) | ((unsigned)f2b(y[3]) << 16);
    unsigned p2 = (unsigned)f2b(y[4]) | ((unsigned)f2b(y[5]) << 16);
    unsigned p3 = (unsigned)f2b(y[6]) | ((unsigned)f2b(y[7]) << 16);
    *(uint4*)(hb + (size_t)n * HID + c0) = make_uint4(p0, p1, p2, p3);
  }
}

// ---------------- GCN head ----------------
__global__ __launch_bounds__(256) void k_xw(const float* __restrict__ h,
                                            const float* __restrict__ W,
                                            float* __restrict__ xw, int N) {
  int lane = threadIdx.x & 63;
  int n = blockIdx.x * 4 + (threadIdx.x >> 6);
  if (n >= N) return;
  const float* hr = h + (size_t)n * HID;
  float v = hr[lane] * W[lane] + hr[64 + lane] * W[64 + lane];
  v = wsum(v);
  if (lane == 0) xw[n] = v;
}

__global__ __launch_bounds__(256) void k_gcn(const int* __restrict__ rowptr,
                                             const int* __restrict__ csr,
                                             const float* __restrict__ xw,
                                             const float* __restrict__ dinv,
                                             const float* __restrict__ gcn_b,
                                             float* __restrict__ out, int N) {
  int n = blockIdx.x * blockDim.x + threadIdx.x;
  if (n >= N) return;
  float acc = 0.f;
  int beg = rowptr[n], end = rowptr[n + 1];
  for (int e = beg; e < end; ++e) {
    int s = csr[e];
    acc += xw[s] * dinv[s];
  }
  float z = acc * dinv[n] + gcn_b[0];
  out[n] = 1.f / (1.f + expf(-z));
}

extern "C" void kernel_launch(void* const* d_in, const int* in_sizes, int n_in,
                              void* d_out, int out_size, void* d_ws, size_t ws_size,
                              hipStream_t stream) {
  const float* x = (const float*)d_in[0];
  const int* ei = (const int*)d_in[1];
  const float* proj_W = (const float*)d_in[2];
  const float* proj_b = (const float*)d_in[3];
  const float* gat_W = (const float*)d_in[4];
  const float* gat_as = (const float*)d_in[5];
  const float* gat_ad = (const float*)d_in[6];
  const float* gat_bias = (const float*)d_in[7];
  const float* ln_g = (const float*)d_in[8];
  const float* ln_b = (const float*)d_in[9];
  const float* gcn_W = (const float*)d_in[10];
  const float* gcn_b = (const float*)d_in[11];
  float* out = (float*)d_out;

  const int N = in_sizes[0] / INDIM;  // 40000
  const int E = in_sizes[1] / 2;      // 320000
  const int TOT = E + N;

  size_t off = 0;
  auto alloc = [&](size_t bytes) {
    void* p = (char*)d_ws + off;
    off += (bytes + 255) & ~(size_t)255;
    return p;
  };
  float* h = (float*)alloc((size_t)MPAD * HID * 4);
  unsigned short* hb = (unsigned short*)alloc((size_t)MPAD * HID * 2);
  unsigned short* xhb = (unsigned short*)alloc((size_t)MPAD * HEADS * HID * 2);
  unsigned short* WtP = (unsigned short*)alloc((size_t)HID * INDIM * 2);
  unsigned short* WtG = (unsigned short*)alloc((size_t)NGAT * (HEADS * HID) * HID * 2);
  float* a_s = (float*)alloc((size_t)MPAD * HEADS * 4);
  float* a_d = (float*)alloc((size_t)MPAD * HEADS * 4);
  int* deg = (int*)alloc((size_t)N * 4);
  int* rowptr = (int*)alloc((size_t)(N + 1) * 4);
  int* cursor = (int*)alloc((size_t)N * 4);
  int* csr = (int*)alloc((size_t)TOT * 4);
  int* bsums = (int*)alloc(1024);
  float* dinv = (float*)alloc((size_t)N * 4);
  float* xw = (float*)alloc((size_t)N * 4);
  (void)ws_size;

  const int NBLK = (N + 255) / 256;
  const int EBLK = (TOT + 255) / 256;
  const int WBLK = (N + 3) / 4;

  // CSR build
  hipMemsetAsync(deg, 0, (size_t)N * 4, stream);
  k_deg<<<EBLK, 256, 0, stream>>>(ei, E, N, deg);
  k_scan1<<<NBLK, 256, 0, stream>>>(deg, N, bsums);
  k_scan2<<<1, 1, 0, stream>>>(bsums, NBLK, rowptr, N);
  k_scan3<<<NBLK, 256, 0, stream>>>(deg, N, bsums, rowptr, cursor, dinv);
  k_fill<<<EBLK, 256, 0, stream>>>(ei, E, N, cursor, csr);

  // weight transposes
  k_wt<<<(INDIM * HID + 255) / 256, 256, 0, stream>>>(proj_W, WtP, INDIM, HID);
  k_wt3<<<(NGAT * HID * HEADS * HID + 255) / 256, 256, 0, stream>>>(gat_W, WtG);

  // projection: h = x @ proj_W + proj_b (reads fp32 x directly)
  k_mm<INDIM, true, false, true><<<dim3(MPAD / 128, 1), 256, 0, stream>>>(
      x, WtP, proj_b, nullptr, nullptr, nullptr, nullptr, h, hb, HID, N);

  for (int i = 0; i < NGAT; ++i) {
    k_mm<HID, false, true, false><<<dim3(MPAD / 128, (HEADS * HID) / 128), 256, 0, stream>>>(
        hb, WtG + (size_t)i * (HEADS * HID) * HID, nullptr,
        gat_as + (size_t)i * HEADS * HID, gat_ad + (size_t)i * HEADS * HID,
        a_s, a_d, nullptr, xhb, HEADS * HID, N);
    k_gat_agg<<<WBLK, 256, 0, stream>>>(rowptr, csr, xhb, a_s, a_d, h, hb,
                                        gat_bias + (size_t)i * HID,
                                        ln_g + (size_t)i * HID,
                                        ln_b + (size_t)i * HID, N);
  }

  // GCN head
  k_xw<<<WBLK, 256, 0, stream>>>(h, gcn_W, xw, N);
  k_gcn<<<NBLK, 256, 0, stream>>>(rowptr, csr, xw, dinv, gcn_b, out, N);
}